// Round 1
// baseline (1433.535 us; speedup 1.0000x reference)
//
#include <hip/hip_runtime.h>
#include <math.h>

#define SS 128
#define BB 64
#define VV 32000
#define EE 32
#define HH 16
#define NROW (SS*BB)   // 8192
#define RT 16          // rows per block in lse/out kernels

// ---------------------------------------------------------------------------
// Kernel 1: Elman recurrence. One 64-lane wave per batch element.
// Lane j (j = lane & 15) owns h_j; weight columns live in registers;
// cross-lane data (x row, previous h) moves via __shfl (wave = 64 lanes).
// Writes Hmat[(t*B + b)*H + j] for all t.
// ---------------------------------------------------------------------------
__global__ __launch_bounds__(64) void rnn_recurrence(
        const int*   __restrict__ idx,     // [S,B]
        const float* __restrict__ lookup,  // [V,E]
        const float* __restrict__ Wx,      // [E,H]
        const float* __restrict__ Wh,      // [H,H]
        const float* __restrict__ h0,      // [B,H]
        float*       __restrict__ Hmat) {  // [S*B,H]
    const int b    = blockIdx.x;
    const int lane = threadIdx.x;          // 0..63
    const int j    = lane & (HH - 1);      // lanes >=16 duplicate lanes 0..15

    float wxj[EE];
    #pragma unroll
    for (int e = 0; e < EE; ++e) wxj[e] = Wx[e * HH + j];
    float whj[HH];
    #pragma unroll
    for (int k = 0; k < HH; ++k) whj[k] = Wh[k * HH + j];

    float hj = h0[b * HH + j];

    for (int t = 0; t < SS; ++t) {
        const int token = idx[t * BB + b];               // block-uniform -> s_load
        const float xv = lookup[token * EE + (lane & (EE - 1))]; // lanes 0..31 carry x

        float a0 = 0.f, a1 = 0.f, a2 = 0.f, a3 = 0.f;    // 4 chains for ILP
        #pragma unroll
        for (int e = 0; e < EE; e += 4) {
            a0 += __shfl(xv, e)     * wxj[e];
            a1 += __shfl(xv, e + 1) * wxj[e + 1];
            a2 += __shfl(xv, e + 2) * wxj[e + 2];
            a3 += __shfl(xv, e + 3) * wxj[e + 3];
        }
        #pragma unroll
        for (int k = 0; k < HH; k += 4) {
            a0 += __shfl(hj, k)     * whj[k];
            a1 += __shfl(hj, k + 1) * whj[k + 1];
            a2 += __shfl(hj, k + 2) * whj[k + 2];
            a3 += __shfl(hj, k + 3) * whj[k + 3];
        }
        hj = tanhf((a0 + a1) + (a2 + a3));
        if (lane < HH) Hmat[(t * BB + b) * HH + j] = hj;
    }
}

// ---------------------------------------------------------------------------
// Kernel 2: per-row log-sum-exp of logits = Hmat[row,:] @ Wo.
// Block handles RT=16 rows x all of V. Wo columns loaded as float4 (16B/lane);
// h rows addressed wave-uniformly -> scalar loads -> SGPR operands for FMA.
// Logits are bounded (|l| < ~2), so no max-shift is needed: exp can't overflow.
// ---------------------------------------------------------------------------
__global__ __launch_bounds__(256) void rnn_lse(
        const float* __restrict__ Hmat,   // [NROW,H]
        const float* __restrict__ Wo,     // [H,V]
        float*       __restrict__ lse) {  // [NROW]
    const int row0 = blockIdx.x * RT;
    const int tid  = threadIdx.x;

    float s[RT];
    #pragma unroll
    for (int r = 0; r < RT; ++r) s[r] = 0.f;

    for (int j = tid; j < VV / 4; j += 256) {
        float4 wc[HH];
        #pragma unroll
        for (int k = 0; k < HH; ++k)
            wc[k] = ((const float4*)(Wo + k * VV))[j];
        #pragma unroll
        for (int r = 0; r < RT; ++r) {
            const float* h = Hmat + (row0 + r) * HH;  // uniform address -> s_load
            float l0 = 0.f, l1 = 0.f, l2 = 0.f, l3 = 0.f;
            #pragma unroll
            for (int k = 0; k < HH; ++k) {
                const float hk = h[k];
                l0 += hk * wc[k].x; l1 += hk * wc[k].y;
                l2 += hk * wc[k].z; l3 += hk * wc[k].w;
            }
            s[r] += (__expf(l0) + __expf(l1)) + (__expf(l2) + __expf(l3));
        }
    }

    // block reduction: wave shuffle-reduce, then cross-wave via LDS
    #pragma unroll
    for (int r = 0; r < RT; ++r) {
        float v = s[r];
        #pragma unroll
        for (int off = 32; off >= 1; off >>= 1)
            v += __shfl_down(v, off);
        s[r] = v;
    }
    __shared__ float red[4][RT];
    const int wave = tid >> 6;
    if ((tid & 63) == 0) {
        #pragma unroll
        for (int r = 0; r < RT; ++r) red[wave][r] = s[r];
    }
    __syncthreads();
    if (tid < RT) {
        const float tot = (red[0][tid] + red[1][tid]) + (red[2][tid] + red[3][tid]);
        lse[row0 + tid] = __logf(tot);
    }
}

// ---------------------------------------------------------------------------
// Kernel 3: recompute logits, subtract lse, stream out[row, v] as float4.
// Write-bound (~1.05 GB); GEMM recompute overlaps the stores.
// ---------------------------------------------------------------------------
__global__ __launch_bounds__(256) void rnn_out(
        const float* __restrict__ Hmat,
        const float* __restrict__ Wo,
        const float* __restrict__ lse,
        float*       __restrict__ out) {  // [NROW, V]
    const int row0 = blockIdx.x * RT;
    const int tid  = threadIdx.x;

    for (int j = tid; j < VV / 4; j += 256) {
        float4 wc[HH];
        #pragma unroll
        for (int k = 0; k < HH; ++k)
            wc[k] = ((const float4*)(Wo + k * VV))[j];
        #pragma unroll
        for (int r = 0; r < RT; ++r) {
            const int row = row0 + r;
            const float* h = Hmat + row * HH;          // uniform -> s_load
            float l0 = 0.f, l1 = 0.f, l2 = 0.f, l3 = 0.f;
            #pragma unroll
            for (int k = 0; k < HH; ++k) {
                const float hk = h[k];
                l0 += hk * wc[k].x; l1 += hk * wc[k].y;
                l2 += hk * wc[k].z; l3 += hk * wc[k].w;
            }
            const float m = lse[row];                  // uniform -> s_load
            float4 o = make_float4(l0 - m, l1 - m, l2 - m, l3 - m);
            ((float4*)(out + (size_t)row * VV))[j] = o;
        }
    }
}

// ---------------------------------------------------------------------------
extern "C" void kernel_launch(void* const* d_in, const int* in_sizes, int n_in,
                              void* d_out, int out_size, void* d_ws, size_t ws_size,
                              hipStream_t stream) {
    const int*   idx    = (const int*)  d_in[0];  // [S,B] int32
    const float* lookup = (const float*)d_in[1];  // [V,E]
    const float* Wx     = (const float*)d_in[2];  // [E,H]
    const float* Wh     = (const float*)d_in[3];  // [H,H]
    const float* Wo     = (const float*)d_in[4];  // [H,V]
    const float* h0     = (const float*)d_in[5];  // [B,H]
    float* out = (float*)d_out;

    float* Hmat = (float*)d_ws;            // NROW*H floats = 512 KB
    float* lse  = Hmat + (size_t)NROW * HH; // NROW floats  =  32 KB

    rnn_recurrence<<<BB, 64, 0, stream>>>(idx, lookup, Wx, Wh, h0, Hmat);
    rnn_lse<<<NROW / RT, 256, 0, stream>>>(Hmat, Wo, lse);
    rnn_out<<<NROW / RT, 256, 0, stream>>>(Hmat, Wo, lse, out);
}